// Round 8
// baseline (221.849 us; speedup 1.0000x reference)
//
#include <hip/hip_runtime.h>

// LSTM forecast: B=1024, S=512, I=1, H=50.
// R8: latency-bound diagnosis (R1-R7 all ~200us across wildly different
// encodings; 1 wave/SIMD, VALUBusy ~60%, chain ~900cyc/step). Fix = raise
// waves/SIMD: one batch per BLOCK of 2 waves (2048 waves = 2/SIMD).
//   wave0: gates i,g + cell state + h publish. wave1: gates f,o -> publishes
//   post-activation (sf,so). 2 barriers/step. Sibling waves on each SIMD
//   come from different blocks (phases drift) and fill each other's stalls.
// Matmul: 25 fdot2 per gate on f16-packed pre-scaled weights (abs err 2e-3
// proven R1-R7), tree-split 13+12 to halve dot-chain depth.

typedef _Float16 half2v __attribute__((ext_vector_type(2)));

#define LOG2E 1.44269504088896340736f
#define B_ 1024
#define S_ 512
#define H_ 50

__device__ __forceinline__ float rcp_(float x) { return __builtin_amdgcn_rcpf(x); }
__device__ __forceinline__ float ex2_(float x) { return __builtin_amdgcn_exp2f(x); }
__device__ __forceinline__ float fdot2_(unsigned hp, half2v w, float acc) {
    return __builtin_amdgcn_fdot2(__builtin_bit_cast(half2v, hp), w, acc, false);
}

// Pack W_hh into [gate][pair m][lane] f16-pairs, pre-scaled by activation
// log2 factors (i,f,o: -log2e ; g: +2*log2e). Also pre-scale W_ih and biases.
__global__ void lstm_pack(const float* __restrict__ W_ih, const float* __restrict__ W_hh,
                          const float* __restrict__ b_ih, const float* __restrict__ b_hh,
                          unsigned* __restrict__ wpk, float* __restrict__ wih_pk,
                          float* __restrict__ bias_pk)
{
    int tid = blockIdx.x * blockDim.x + threadIdx.x;
    int stride = blockDim.x * gridDim.x;
    for (int p = tid; p < 4 * 25 * 64; p += stride) {
        int j = p & 63;
        int m = (p >> 6) % 25;
        int g = p / (25 * 64);
        float s = (g == 2) ? (2.0f * LOG2E) : (-LOG2E);
        float a = 0.0f, bb = 0.0f;
        if (j < H_) {
            int row = g * H_ + j;
            a  = s * W_hh[row * H_ + 2 * m];
            bb = s * W_hh[row * H_ + 2 * m + 1];
        }
        half2v hv;
        hv.x = (_Float16)a;
        hv.y = (_Float16)bb;
        wpk[p] = __builtin_bit_cast(unsigned, hv);
    }
    for (int p = tid; p < 4 * 64; p += stride) {
        int j = p & 63;
        int g = p >> 6;
        float s = (g == 2) ? (2.0f * LOG2E) : (-LOG2E);
        float wi = 0.0f, bb = 0.0f;
        if (j < H_) {
            int row = g * H_ + j;
            wi = s * W_ih[row];
            bb = s * (b_ih[row] + b_hh[row]);
        }
        wih_pk[p] = wi;
        bias_pk[p] = bb;
    }
}

__global__
__attribute__((amdgpu_flat_work_group_size(128, 128)))
__attribute__((amdgpu_waves_per_eu(2)))
void lstm_main(const float* __restrict__ x, const float* __restrict__ h0,
               const float* __restrict__ c0, const float* __restrict__ fc_w,
               const float* __restrict__ fc_b, const unsigned* __restrict__ wpk,
               const float* __restrict__ wih_pk, const float* __restrict__ bias_pk,
               float* __restrict__ out)
{
    const int b   = blockIdx.x;
    const int tid = threadIdx.x;
    const int j   = tid & 63;
    const int wid = tid >> 6;

    __shared__ unsigned hs16[32];   // packed f16x2 h-pairs, slot m = (h[2m],h[2m+1])
    __shared__ float2   sfso[64];   // wave1 -> wave0: (sigmoid(f), sigmoid(o)) per j

    // wave0 -> gates 0 (i) and 2 (g); wave1 -> gates 1 (f) and 3 (o)
    const int gA = wid;       // i / f  (sigmoid, scale -log2e folded)
    const int gB = wid + 2;   // g / o  (g: tanh, +2log2e; o: sigmoid, -log2e)

    half2v wA[25], wB[25];
    #pragma unroll
    for (int m = 0; m < 25; ++m) {
        wA[m] = __builtin_bit_cast(half2v, wpk[(gA * 25 + m) * 64 + j]);
        wB[m] = __builtin_bit_cast(half2v, wpk[(gB * 25 + m) * 64 + j]);
    }
    float wihA = wih_pk[gA * 64 + j], wihB = wih_pk[gB * 64 + j];
    float bsA  = bias_pk[gA * 64 + j], bsB = bias_pk[gB * 64 + j];

    float h = (j < H_) ? h0[b * H_ + j] : 0.0f;
    float c = (j < H_) ? c0[b * H_ + j] : 0.0f;

    if (wid == 0) {
        // publish initial h-pairs: even lane 2m packs (h[2m], h[2m+1])
        int hn_ = __builtin_amdgcn_update_dpp(0, __builtin_bit_cast(int, h),
                                              0xB1, 0xF, 0xF, true);
        unsigned hpk = __builtin_bit_cast(unsigned,
            __builtin_amdgcn_cvt_pkrtz(h, __builtin_bit_cast(float, hn_)));
        if ((j & 1) == 0 && j < H_) hs16[j >> 1] = hpk;
    }
    __syncthreads();
    unsigned hp[25];
    #pragma unroll
    for (int m = 0; m < 25; ++m) hp[m] = hs16[m];

    const float* __restrict__ xrow = x + b * S_;
    float xt = xrow[0];

    for (int s = 0; s < S_; ++s) {
        float xt_n = xrow[s + 1 < S_ ? s + 1 : S_ - 1];

        // 2 gates x tree-split (13+12) = 4 independent fdot2 chains
        float aA1 = __builtin_fmaf(xt, wihA, bsA), aA2 = 0.0f;
        float aB1 = __builtin_fmaf(xt, wihB, bsB), aB2 = 0.0f;
        #pragma unroll
        for (int m = 0; m < 13; ++m) {
            aA1 = fdot2_(hp[m], wA[m], aA1);
            aB1 = fdot2_(hp[m], wB[m], aB1);
        }
        #pragma unroll
        for (int m = 13; m < 25; ++m) {
            aA2 = fdot2_(hp[m], wA[m], aA2);
            aB2 = fdot2_(hp[m], wB[m], aB2);
        }
        float aA = aA1 + aA2;   // w0: i-arg   w1: f-arg   (pre-scaled -log2e)
        float aB = aB1 + aB2;   // w0: g-arg(+2log2e)  w1: o-arg(-log2e)

        float eA = ex2_(aA); float sA = rcp_(1.0f + eA);  // sigmoid(i) / sigmoid(f)
        float eB = ex2_(aB); float rB = rcp_(1.0f + eB);  // g-partial / sigmoid(o)

        if (wid == 1 && j < H_) sfso[j] = make_float2(sA, rB);  // (sf, so)
        __syncthreads();   // barrier 1: gates f,o visible to wave0

        if (wid == 0) {
            float tg = __builtin_fmaf(-2.0f, rB, 1.0f);          // tanh(g)
            float2 t = sfso[j < H_ ? j : 0];                     // (sf, so)
            c = __builtin_fmaf(t.x, c, sA * tg);
            float ec = ex2_((2.0f * LOG2E) * c);
            float tc = __builtin_fmaf(-2.0f, rcp_(1.0f + ec), 1.0f);  // tanh(c)
            h = t.y * tc;
            int hn_ = __builtin_amdgcn_update_dpp(0, __builtin_bit_cast(int, h),
                                                  0xB1, 0xF, 0xF, true);
            unsigned hpk = __builtin_bit_cast(unsigned,
                __builtin_amdgcn_cvt_pkrtz(h, __builtin_bit_cast(float, hn_)));
            if ((j & 1) == 0 && j < H_) hs16[j >> 1] = hpk;
        }
        __syncthreads();   // barrier 2: new h visible to both waves

        #pragma unroll
        for (int m = 0; m < 25; ++m) hp[m] = hs16[m];
        xt = xt_n;
    }

    // outputs: [out (B,1)] [h_n (1,B,H)] [c_n (1,B,H)] concatenated
    if (wid == 0) {
        if (j < H_) {
            out[B_ + b * H_ + j]           = h;
            out[B_ + B_ * H_ + b * H_ + j] = c;
        }
        float p = (j < H_) ? h * fc_w[j] : 0.0f;
        #pragma unroll
        for (int off = 32; off > 0; off >>= 1) p += __shfl_xor(p, off);
        if (j == 0) out[b] = p + fc_b[0];
    }
}

extern "C" void kernel_launch(void* const* d_in, const int* in_sizes, int n_in,
                              void* d_out, int out_size, void* d_ws, size_t ws_size,
                              hipStream_t stream)
{
    const float* x    = (const float*)d_in[0];
    const float* h0   = (const float*)d_in[1];
    const float* c0   = (const float*)d_in[2];
    const float* W_ih = (const float*)d_in[3];
    const float* W_hh = (const float*)d_in[4];
    const float* b_ih = (const float*)d_in[5];
    const float* b_hh = (const float*)d_in[6];
    const float* fc_w = (const float*)d_in[7];
    const float* fc_b = (const float*)d_in[8];
    float* out = (float*)d_out;

    unsigned* wpk  = (unsigned*)d_ws;                               // 6400 u32 = 25.6 KB
    float* wih_pk  = (float*)((char*)d_ws + 6400 * 4);              // 256 f32
    float* bias_pk = (float*)((char*)d_ws + 6400 * 4 + 256 * 4);    // 256 f32

    lstm_pack<<<16, 256, 0, stream>>>(W_ih, W_hh, b_ih, b_hh, wpk, wih_pk, bias_pk);
    lstm_main<<<B_, 128, 0, stream>>>(x, h0, c0, fc_w, fc_b, wpk, wih_pk, bias_pk, out);
}